// Round 6
// baseline (531.247 us; speedup 1.0000x reference)
//
#include <hip/hip_runtime.h>
#include <hip/hip_bf16.h>
#include <math.h>

#define NN 50000
#define NE 800000
#define NB 512
#define FIN 74
#define HD 64
#define BN_EPS 1e-5f

#define SCHUNK 512
#define NCHUNK ((NN + SCHUNK - 1) / SCHUNK)  // 98

#define CHUNK 32
#define NBLK ((NN + CHUNK - 1) / CHUNK)  // 1563

// ---------------- CSR build (padded to multiple of 4 edges/row) ----------------

__global__ void csr_zero_kernel(int* __restrict__ cnt, int* __restrict__ cnt2,
                                float* __restrict__ stats012,
                                unsigned long long* __restrict__ xw_zrow) {
    int i = blockIdx.x * 256 + threadIdx.x;
    if (i < NN) { cnt[i] = 0; cnt2[i] = 0; }
    if (i < 384) stats012[i] = 0.f;
    if (i < 16) xw_zrow[i] = 0ull;  // XW row NN = 128 B of zeros
}

__global__ void csr_hist_kernel(const int* __restrict__ dst, int* __restrict__ cnt) {
    int e = blockIdx.x * 256 + threadIdx.x;
    if (e < NE) atomicAdd(&cnt[dst[e]], 1);
}

__device__ __forceinline__ int pad4(int d) { return (d + 3) & ~3; }

__global__ void scanA_kernel(const int* __restrict__ cnt, int* __restrict__ bsum) {
    __shared__ int l[SCHUNK];
    int i = blockIdx.x * SCHUNK + threadIdx.x;
    int v = (i < NN) ? pad4(cnt[i]) : 0;
    l[threadIdx.x] = v;
    __syncthreads();
    for (int off = SCHUNK / 2; off; off >>= 1) {
        if (threadIdx.x < off) l[threadIdx.x] += l[threadIdx.x + off];
        __syncthreads();
    }
    if (threadIdx.x == 0) bsum[blockIdx.x] = l[0];
}

__global__ void scanB_kernel(int* __restrict__ bsum) {
    int lane = threadIdx.x;  // 64 threads
    int v0 = (lane < NCHUNK) ? bsum[lane] : 0;
    int v1 = (64 + lane < NCHUNK) ? bsum[64 + lane] : 0;
    int s0 = v0, s1 = v1;
    for (int off = 1; off < 64; off <<= 1) {
        int t0 = __shfl_up(s0, off, 64);
        int t1 = __shfl_up(s1, off, 64);
        if (lane >= off) { s0 += t0; s1 += t1; }
    }
    int tot0 = __shfl(s0, 63, 64);
    if (lane < NCHUNK) bsum[lane] = s0 - v0;
    if (64 + lane < NCHUNK) bsum[64 + lane] = s1 - v1 + tot0;
}

__global__ void scanC_kernel(const int* __restrict__ cnt, const int* __restrict__ bsum,
                             int* __restrict__ row_ptr) {
    __shared__ int l[SCHUNK];
    int i = blockIdx.x * SCHUNK + threadIdx.x;
    int v = (i < NN) ? pad4(cnt[i]) : 0;
    l[threadIdx.x] = v;
    __syncthreads();
    for (int off = 1; off < SCHUNK; off <<= 1) {
        int t = (threadIdx.x >= off) ? l[threadIdx.x - off] : 0;
        __syncthreads();
        l[threadIdx.x] += t;
        __syncthreads();
    }
    int excl = l[threadIdx.x] - v + bsum[blockIdx.x];
    if (i < NN) row_ptr[i] = excl;
    if (i == NN - 1) row_ptr[NN] = excl + v;
}

__global__ void csr_fill_kernel(const int* __restrict__ src, const int* __restrict__ dst,
                                const int* __restrict__ row_ptr, const int* __restrict__ cnt,
                                int* __restrict__ cnt2, int* __restrict__ eidx) {
    int i = blockIdx.x * 256 + threadIdx.x;
    if (i < NE) {
        int d = dst[i];
        int p = row_ptr[d] + atomicAdd(&cnt2[d], 1);
        eidx[p] = src[i];
    }
    if (i < NN) {
        int deg = cnt[i], st = row_ptr[i], pd = pad4(deg);
        for (int j = deg; j < pd; ++j) eidx[st + j] = NN;
    }
}

// ---------------- dense pieces ----------------

// xw = x @ W1 (bf16); res = relu(x @ W2 + rb) (bf16). One pass over x.
template <int K>
__global__ __launch_bounds__(256) void gemm_dual_kernel(
    const float* __restrict__ x, const float* __restrict__ W1, const float* __restrict__ W2,
    const float* __restrict__ rb, __hip_bfloat16* __restrict__ xw,
    __hip_bfloat16* __restrict__ res, int n) {
    __shared__ float sW1[K * HD];
    __shared__ float sW2[K * HD];
    __shared__ float srb[64];
    for (int i = threadIdx.x; i < K * HD; i += 256) { sW1[i] = W1[i]; sW2[i] = W2[i]; }
    if (threadIdx.x < 64) srb[threadIdx.x] = rb[threadIdx.x];
    __syncthreads();
    int wl = threadIdx.x >> 6, col = threadIdx.x & 63;
    for (int row = blockIdx.x * 4 + wl; row < n; row += gridDim.x * 4) {
        const float* xr = x + (size_t)row * K;
        float a1 = 0.f, a2 = srb[col];
#pragma unroll 8
        for (int k = 0; k < K; ++k) {
            float xv = xr[k];
            a1 = fmaf(xv, sW1[k * HD + col], a1);
            a2 = fmaf(xv, sW2[k * HD + col], a2);
        }
        xw[(size_t)row * HD + col] = __float2bfloat16(a1);
        res[(size_t)row * HD + col] = __float2bfloat16(fmaxf(a2, 0.f));
    }
}

// BN fold for layer l>=1
__global__ void fold_kernel(const float* __restrict__ stats, const float* __restrict__ g,
                            const float* __restrict__ be, const float* __restrict__ W,
                            const float* __restrict__ rW, const float* __restrict__ rb,
                            float* __restrict__ Wp, float* __restrict__ rWp,
                            float* __restrict__ shiftW, float* __restrict__ rbp) {
    __shared__ float sc[64], sh[64];
    int t = threadIdx.x;
    if (t < 64) {
        float mean = stats[t] / (float)NN;
        float var = stats[64 + t] / (float)NN - mean * mean;
        float scale = g[t] * rsqrtf(var + BN_EPS);
        sc[t] = scale;
        sh[t] = be[t] - mean * scale;
    }
    __syncthreads();
    for (int i = t; i < 64 * 64; i += 256) {
        int k = i >> 6;
        Wp[i] = sc[k] * W[i];
        rWp[i] = sc[k] * rW[i];
    }
    if (t < 64) {
        float sw = 0.f, srw = 0.f;
        for (int k = 0; k < 64; ++k) {
            sw = fmaf(sh[k], W[k * 64 + t], sw);
            srw = fmaf(sh[k], rW[k * 64 + t], srw);
        }
        shiftW[t] = sw;
        rbp[t] = rb[t] + srw;
    }
}

__device__ __forceinline__ float bf_lo(unsigned int p) { return __uint_as_float(p << 16); }
__device__ __forceinline__ float bf_hi(unsigned int p) { return __uint_as_float(p & 0xffff0000u); }

// gather state: 4x 8-B xw loads (16 edges) + res value, per row
struct GState {
    unsigned long long p0, p1, p2, p3;
    unsigned int rv;
    int ng, lo, dg;
};

__device__ __forceinline__ void g_issue(GState& S, int rr, int r0, int rlim,
                                        const int* __restrict__ sRP,
                                        const int* __restrict__ sDeg,
                                        const int* __restrict__ geidx,
                                        const unsigned long long* __restrict__ XWu,
                                        const unsigned short* __restrict__ resu,
                                        int q, int c16, int c) {
    S.p0 = S.p1 = S.p2 = S.p3 = 0ull;
    S.rv = 0u;
    S.ng = 0; S.lo = 0; S.dg = 0;
    if (rr < rlim) {
        int lo = sRP[rr - r0];
        int plen = sRP[rr - r0 + 1] - lo;
        S.lo = lo;
        S.ng = plen >> 2;
        S.dg = sDeg[rr - r0];
        S.rv = resu[(size_t)rr * HD + c];
        if (S.ng > 0) S.p0 = XWu[(size_t)geidx[lo + q] * 16 + c16];
        if (S.ng > 1) S.p1 = XWu[(size_t)geidx[lo + 4 + q] * 16 + c16];
        if (S.ng > 2) S.p2 = XWu[(size_t)geidx[lo + 8 + q] * 16 + c16];
        if (S.ng > 3) S.p3 = XWu[(size_t)geidx[lo + 12 + q] * 16 + c16];
    }
}

__device__ __forceinline__ void g_consume(const GState& S, int rr, int rlim,
                                          const int* __restrict__ geidx,
                                          const unsigned long long* __restrict__ XWu,
                                          const float* __restrict__ sb,
                                          const float* __restrict__ ssw,
                                          float* __restrict__ hout,
                                          int q, int c16, int c,
                                          float& ssum, float& ssum2) {
    if (rr >= rlim) return;
    unsigned l0 = (unsigned)S.p0, h0 = (unsigned)(S.p0 >> 32);
    unsigned l1 = (unsigned)S.p1, h1 = (unsigned)(S.p1 >> 32);
    unsigned l2 = (unsigned)S.p2, h2 = (unsigned)(S.p2 >> 32);
    unsigned l3 = (unsigned)S.p3, h3 = (unsigned)(S.p3 >> 32);
    float a0 = (bf_lo(l0) + bf_lo(l1)) + (bf_lo(l2) + bf_lo(l3));
    float a1 = (bf_hi(l0) + bf_hi(l1)) + (bf_hi(l2) + bf_hi(l3));
    float a2 = (bf_lo(h0) + bf_lo(h1)) + (bf_lo(h2) + bf_lo(h3));
    float a3 = (bf_hi(h0) + bf_hi(h1)) + (bf_hi(h2) + bf_hi(h3));
    for (int k = 4; k < S.ng; ++k) {  // rare: degree > 16
        unsigned long long u = XWu[(size_t)geidx[S.lo + 4 * k + q] * 16 + c16];
        unsigned lo = (unsigned)u, hi = (unsigned)(u >> 32);
        a0 += bf_lo(lo); a1 += bf_hi(lo); a2 += bf_lo(hi); a3 += bf_hi(hi);
    }
    a0 += __shfl_xor(a0, 16, 64); a0 += __shfl_xor(a0, 32, 64);
    a1 += __shfl_xor(a1, 16, 64); a1 += __shfl_xor(a1, 32, 64);
    a2 += __shfl_xor(a2, 16, 64); a2 += __shfl_xor(a2, 32, 64);
    a3 += __shfl_xor(a3, 16, 64); a3 += __shfl_xor(a3, 32, 64);
    float t0 = __shfl(a0, c >> 2, 64);
    float t1 = __shfl(a1, c >> 2, 64);
    float t2 = __shfl(a2, c >> 2, 64);
    float t3 = __shfl(a3, c >> 2, 64);
    float val = (c & 2) ? ((c & 1) ? t3 : t2) : ((c & 1) ? t1 : t0);
    float agg = val + fmaf((float)S.dg, ssw[c], sb[c]);
    float resv = __uint_as_float(S.rv << 16);  // already relu'd in gemm_dual
    float hv = fmaxf(agg, 0.f) + resv;
    hout[(size_t)rr * HD + c] = hv;
    ssum += hv;
    ssum2 += hv * hv;
}

// fused aggregation: h = relu(gather + deg*shiftW + b) + res; stats += (h, h^2)
__global__ __launch_bounds__(256) void fused_agg_kernel(
    const __hip_bfloat16* __restrict__ xw, const __hip_bfloat16* __restrict__ res,
    const float* __restrict__ b, const float* __restrict__ shiftW,
    const int* __restrict__ row_ptr, const int* __restrict__ geidx,
    const int* __restrict__ degs, float* __restrict__ hout, float* __restrict__ stats, int n) {
    __shared__ int sRP[CHUNK + 1];
    __shared__ int sDeg[CHUNK];
    __shared__ float sb[64], ssw[64];
    __shared__ float ls[256], ls2[256];

    int r0 = blockIdx.x * CHUNK;
    int rlim = (r0 + CHUNK < n) ? r0 + CHUNK : n;
    int tid = threadIdx.x;

    if (tid <= CHUNK) {
        int rp = r0 + tid;
        sRP[tid] = row_ptr[(rp < NN) ? rp : NN];
    }
    if (tid >= 64 && tid < 64 + CHUNK) {
        int rp = r0 + (tid - 64);
        sDeg[tid - 64] = (rp < n) ? degs[rp] : 0;
    }
    if (tid >= 128 && tid < 192) {
        sb[tid - 128] = b[tid - 128];
        ssw[tid - 128] = shiftW ? shiftW[tid - 128] : 0.f;
    }
    __syncthreads();

    const unsigned long long* XWu = (const unsigned long long*)xw;
    const unsigned short* resu = (const unsigned short*)res;
    int wl = tid >> 6, c = tid & 63;
    int q = c >> 4;    // edge-quad 0..3
    int c16 = c & 15;  // 8-B chunk of the 128-B row
    float ssum = 0.f, ssum2 = 0.f;
    int rr0 = r0 + wl * 8;

    GState A, B, C, D;
    g_issue(A, rr0 + 0, r0, rlim, sRP, sDeg, geidx, XWu, resu, q, c16, c);
    g_issue(B, rr0 + 1, r0, rlim, sRP, sDeg, geidx, XWu, resu, q, c16, c);
    g_issue(C, rr0 + 2, r0, rlim, sRP, sDeg, geidx, XWu, resu, q, c16, c);
    g_issue(D, rr0 + 3, r0, rlim, sRP, sDeg, geidx, XWu, resu, q, c16, c);
    g_consume(A, rr0 + 0, rlim, geidx, XWu, sb, ssw, hout, q, c16, c, ssum, ssum2);
    g_issue(A, rr0 + 4, r0, rlim, sRP, sDeg, geidx, XWu, resu, q, c16, c);
    g_consume(B, rr0 + 1, rlim, geidx, XWu, sb, ssw, hout, q, c16, c, ssum, ssum2);
    g_issue(B, rr0 + 5, r0, rlim, sRP, sDeg, geidx, XWu, resu, q, c16, c);
    g_consume(C, rr0 + 2, rlim, geidx, XWu, sb, ssw, hout, q, c16, c, ssum, ssum2);
    g_issue(C, rr0 + 6, r0, rlim, sRP, sDeg, geidx, XWu, resu, q, c16, c);
    g_consume(D, rr0 + 3, rlim, geidx, XWu, sb, ssw, hout, q, c16, c, ssum, ssum2);
    g_issue(D, rr0 + 7, r0, rlim, sRP, sDeg, geidx, XWu, resu, q, c16, c);
    g_consume(A, rr0 + 4, rlim, geidx, XWu, sb, ssw, hout, q, c16, c, ssum, ssum2);
    g_consume(B, rr0 + 5, rlim, geidx, XWu, sb, ssw, hout, q, c16, c, ssum, ssum2);
    g_consume(C, rr0 + 6, rlim, geidx, XWu, sb, ssw, hout, q, c16, c, ssum, ssum2);
    g_consume(D, rr0 + 7, rlim, geidx, XWu, sb, ssw, hout, q, c16, c, ssum, ssum2);

    ls[tid] = ssum;
    ls2[tid] = ssum2;
    __syncthreads();
    if (wl == 0) {
        float a = ls[c] + ls[64 + c] + ls[128 + c] + ls[192 + c];
        float a2 = ls2[c] + ls2[64 + c] + ls2[128 + c] + ls2[192 + c];
        atomicAdd(&stats[c], a);
        atomicAdd(&stats[64 + c], a2);
    }
}

// ---------------- readout ----------------

__global__ void readout_init_kernel(float* __restrict__ hsum, unsigned int* __restrict__ hmax,
                                    const float* __restrict__ stats, const float* __restrict__ g,
                                    const float* __restrict__ be, float* __restrict__ ss) {
    int idx = blockIdx.x * 256 + threadIdx.x;
    if (idx < NB * HD) {
        hsum[idx] = 0.f;
        hmax[idx] = 0x007FFFFFu;  // encoded(-inf)
    }
    if (blockIdx.x == 0 && threadIdx.x < 64) {
        int c = threadIdx.x;
        float mean = stats[c] / (float)NN;
        float var = stats[64 + c] / (float)NN - mean * mean;
        float scale = g[c] * rsqrtf(var + BN_EPS);
        ss[c] = scale;
        ss[64 + c] = be[c] - mean * scale;
    }
}

#define RNODES 16

__device__ __forceinline__ void ro_flush(float* hsum, unsigned int* hmax, int g, int c,
                                         float accS, float accM) {
    atomicAdd(&hsum[g * HD + c], accS);
    unsigned int bits = __float_as_uint(accM);
    unsigned int enc = (bits & 0x80000000u) ? ~bits : (bits | 0x80000000u);
    atomicMax(&hmax[g * HD + c], enc);
}

__global__ __launch_bounds__(256) void readout_kernel(
    const float* __restrict__ h, const int* __restrict__ gid, const float* __restrict__ ss,
    const float* __restrict__ awW, const float* __restrict__ awb, float* __restrict__ hsum,
    unsigned int* __restrict__ hmax, int n) {
    int wid = blockIdx.x * 4 + (threadIdx.x >> 6);
    int c = threadIdx.x & 63;
    int r0 = wid * RNODES;
    if (r0 >= n) return;
    int r1 = r0 + RNODES;
    if (r1 > n) r1 = n;
    float aw = awW[c], ab = awb[0];
    float sA = ss[c], sB = ss[64 + c];
    int cur = gid[r0];
    float accS = 0.f, accM = -__builtin_inff();
    for (int r = r0; r < r1; ++r) {
        int g = gid[r];
        if (g != cur) {
            ro_flush(hsum, hmax, cur, c, accS, accM);
            accS = 0.f;
            accM = -__builtin_inff();
            cur = g;
        }
        float v = fmaf(h[(size_t)r * HD + c], sA, sB);
        float p = v * aw;
        for (int off = 32; off; off >>= 1) p += __shfl_xor(p, off, 64);
        float w = 1.f / (1.f + expf(-(p + ab)));
        accS = fmaf(v, w, accS);
        accM = fmaxf(accM, v);
    }
    ro_flush(hsum, hmax, cur, c, accS, accM);
}

__global__ void final_kernel(const float* __restrict__ hsum, const unsigned int* __restrict__ hmax,
                             const float* __restrict__ outW, const float* __restrict__ outb,
                             float* __restrict__ out) {
    __shared__ float sW[128 * 64];
    for (int i = threadIdx.x; i < 128 * 64; i += 256) sW[i] = outW[i];
    __syncthreads();
    int idx = blockIdx.x * 256 + threadIdx.x;
    if (idx >= NB * HD) return;
    int bi = idx >> 6, o = idx & 63;
    float acc = outb[o];
#pragma unroll 4
    for (int k = 0; k < 64; ++k) acc = fmaf(hsum[bi * 64 + k], sW[k * 64 + o], acc);
#pragma unroll 4
    for (int k = 0; k < 64; ++k) {
        unsigned int e = hmax[bi * 64 + k];
        float m;
        if (e == 0x007FFFFFu) {
            m = 0.f;  // empty graph
        } else {
            m = (e & 0x80000000u) ? __uint_as_float(e ^ 0x80000000u) : __uint_as_float(~e);
        }
        acc = fmaf(m, sW[(64 + k) * 64 + o], acc);
    }
    out[idx] = acc;
}

// ---------------- launch ----------------

extern "C" void kernel_launch(void* const* d_in, const int* in_sizes, int n_in,
                              void* d_out, int out_size, void* d_ws, size_t ws_size,
                              hipStream_t stream) {
    const float* feats = (const float*)d_in[0];
    const int* src = (const int*)d_in[1];
    const int* dst = (const int*)d_in[2];
    const int* gid = (const int*)d_in[3];
    const float* W[3];
    const float* b[3];
    const float* rW[3];
    const float* rb[3];
    const float* g[3];
    const float* be[3];
    for (int l = 0; l < 3; ++l) {
        W[l] = (const float*)d_in[4 + 6 * l + 0];
        b[l] = (const float*)d_in[4 + 6 * l + 1];
        rW[l] = (const float*)d_in[4 + 6 * l + 2];
        rb[l] = (const float*)d_in[4 + 6 * l + 3];
        g[l] = (const float*)d_in[4 + 6 * l + 4];
        be[l] = (const float*)d_in[4 + 6 * l + 5];
    }
    const float* awW = (const float*)d_in[22];
    const float* awb = (const float*)d_in[23];
    const float* outW = (const float*)d_in[24];
    const float* outb = (const float*)d_in[25];
    float* out = (float*)d_out;

    // workspace layout
    __hip_bfloat16* XW = (__hip_bfloat16*)d_ws;                 // (NN+1)*64 bf16 (row NN zeros)
    __hip_bfloat16* RES = XW + (size_t)(NN + 1) * HD;           // NN*64 bf16
    float* P1 = (float*)(RES + (size_t)NN * HD);                // N*64 f32 (h, ping-pong in place)
    float* stats = P1 + (size_t)NN * HD;                        // 3*128
    float* ss2 = stats + 384;                                   // 128
    float* Wp = ss2 + 128;                                      // 4096
    float* rWp = Wp + 4096;                                     // 4096
    float* shW = rWp + 4096;                                    // 64
    float* rbp = shW + 64;                                      // 64
    float* hsum = rbp + 64;                                     // B*64
    unsigned int* hmax = (unsigned int*)(hsum + (size_t)NB * HD);  // B*64
    int* cnt = (int*)(hmax + (size_t)NB * HD);                  // N (real degree)
    int* cnt2 = cnt + NN;                                       // N
    int* row_ptr = cnt2 + NN;                                   // N+1 (padded CSR)
    int* bsum = row_ptr + NN + 1;                               // NCHUNK
    int* eidx = bsum + NCHUNK;                                  // <= NE + 3*NN

    float* stats0 = stats;
    float* stats1 = stats + 128;
    float* stats2 = stats + 256;

    const int EBLK = (NE + 255) / 256;
    const int GEMMBLK = 1280;
    const int ROBLK = (NN + RNODES * 4 - 1) / (RNODES * 4);

    // ---- CSR build (padded) ----
    csr_zero_kernel<<<(NN + 255) / 256, 256, 0, stream>>>(
        cnt, cnt2, stats, (unsigned long long*)(XW + (size_t)NN * HD));
    csr_hist_kernel<<<EBLK, 256, 0, stream>>>(dst, cnt);
    scanA_kernel<<<NCHUNK, SCHUNK, 0, stream>>>(cnt, bsum);
    scanB_kernel<<<1, 64, 0, stream>>>(bsum);
    scanC_kernel<<<NCHUNK, SCHUNK, 0, stream>>>(cnt, bsum, row_ptr);
    csr_fill_kernel<<<EBLK, 256, 0, stream>>>(src, dst, row_ptr, cnt, cnt2, eidx);

    // ---- layer 0 ----
    gemm_dual_kernel<FIN><<<GEMMBLK, 256, 0, stream>>>(feats, W[0], rW[0], rb[0], XW, RES, NN);
    fused_agg_kernel<<<NBLK, 256, 0, stream>>>(XW, RES, b[0], (const float*)nullptr, row_ptr,
                                               eidx, cnt, P1, stats0, NN);

    // ---- layer 1 (fold BN0) ----
    fold_kernel<<<1, 256, 0, stream>>>(stats0, g[0], be[0], W[1], rW[1], rb[1], Wp, rWp, shW, rbp);
    gemm_dual_kernel<HD><<<GEMMBLK, 256, 0, stream>>>(P1, Wp, rWp, rbp, XW, RES, NN);
    fused_agg_kernel<<<NBLK, 256, 0, stream>>>(XW, RES, b[1], shW, row_ptr, eidx, cnt, P1,
                                               stats1, NN);

    // ---- layer 2 (fold BN1) ----
    fold_kernel<<<1, 256, 0, stream>>>(stats1, g[1], be[1], W[2], rW[2], rb[2], Wp, rWp, shW, rbp);
    gemm_dual_kernel<HD><<<GEMMBLK, 256, 0, stream>>>(P1, Wp, rWp, rbp, XW, RES, NN);
    fused_agg_kernel<<<NBLK, 256, 0, stream>>>(XW, RES, b[2], shW, row_ptr, eidx, cnt, P1,
                                               stats2, NN);

    // ---- readout (BN2 on the fly) ----
    readout_init_kernel<<<(NB * HD + 255) / 256, 256, 0, stream>>>(hsum, hmax, stats2, g[2], be[2], ss2);
    readout_kernel<<<ROBLK, 256, 0, stream>>>(P1, gid, ss2, awW, awb, hsum, hmax, NN);
    final_kernel<<<(NB * HD + 255) / 256, 256, 0, stream>>>(hsum, hmax, outW, outb, out);
}

// Round 7
// 449.561 us; speedup vs baseline: 1.1817x; 1.1817x over previous
//
#include <hip/hip_runtime.h>
#include <hip/hip_bf16.h>
#include <math.h>

#define NN 50000
#define NE 800000
#define NB 512
#define FIN 74
#define HD 64
#define BN_EPS 1e-5f

#define SCHUNK 512
#define NCHUNK ((NN + SCHUNK - 1) / SCHUNK)  // 98

#define CHUNK 32
#define NBLK ((NN + CHUNK - 1) / CHUNK)  // 1563

// ---------------- CSR build (padded to multiple of 4 edges/row) ----------------

// also packs layer-0 weights into (W,rW) float2 pairs
__global__ void csr_zero_kernel(int* __restrict__ cnt, int* __restrict__ cnt2,
                                float* __restrict__ stats012,
                                unsigned long long* __restrict__ xw_zrow,
                                const float* __restrict__ W0, const float* __restrict__ rW0,
                                float2* __restrict__ Wpk0) {
    int i = blockIdx.x * 256 + threadIdx.x;
    if (i < NN) { cnt[i] = 0; cnt2[i] = 0; }
    if (i < 384) stats012[i] = 0.f;
    if (i < 16) xw_zrow[i] = 0ull;  // XW row NN = 128 B of zeros
    if (i < FIN * HD) Wpk0[i] = make_float2(W0[i], rW0[i]);
}

__global__ void csr_hist_kernel(const int* __restrict__ dst, int* __restrict__ cnt) {
    int e = blockIdx.x * 256 + threadIdx.x;
    if (e < NE) atomicAdd(&cnt[dst[e]], 1);
}

__device__ __forceinline__ int pad4(int d) { return (d + 3) & ~3; }

__global__ void scanA_kernel(const int* __restrict__ cnt, int* __restrict__ bsum) {
    __shared__ int l[SCHUNK];
    int i = blockIdx.x * SCHUNK + threadIdx.x;
    int v = (i < NN) ? pad4(cnt[i]) : 0;
    l[threadIdx.x] = v;
    __syncthreads();
    for (int off = SCHUNK / 2; off; off >>= 1) {
        if (threadIdx.x < off) l[threadIdx.x] += l[threadIdx.x + off];
        __syncthreads();
    }
    if (threadIdx.x == 0) bsum[blockIdx.x] = l[0];
}

__global__ void scanB_kernel(int* __restrict__ bsum) {
    int lane = threadIdx.x;  // 64 threads
    int v0 = (lane < NCHUNK) ? bsum[lane] : 0;
    int v1 = (64 + lane < NCHUNK) ? bsum[64 + lane] : 0;
    int s0 = v0, s1 = v1;
    for (int off = 1; off < 64; off <<= 1) {
        int t0 = __shfl_up(s0, off, 64);
        int t1 = __shfl_up(s1, off, 64);
        if (lane >= off) { s0 += t0; s1 += t1; }
    }
    int tot0 = __shfl(s0, 63, 64);
    if (lane < NCHUNK) bsum[lane] = s0 - v0;
    if (64 + lane < NCHUNK) bsum[64 + lane] = s1 - v1 + tot0;
}

__global__ void scanC_kernel(const int* __restrict__ cnt, const int* __restrict__ bsum,
                             int* __restrict__ row_ptr) {
    __shared__ int l[SCHUNK];
    int i = blockIdx.x * SCHUNK + threadIdx.x;
    int v = (i < NN) ? pad4(cnt[i]) : 0;
    l[threadIdx.x] = v;
    __syncthreads();
    for (int off = 1; off < SCHUNK; off <<= 1) {
        int t = (threadIdx.x >= off) ? l[threadIdx.x - off] : 0;
        __syncthreads();
        l[threadIdx.x] += t;
        __syncthreads();
    }
    int excl = l[threadIdx.x] - v + bsum[blockIdx.x];
    if (i < NN) row_ptr[i] = excl;
    if (i == NN - 1) row_ptr[NN] = excl + v;
}

__global__ void csr_fill_kernel(const int* __restrict__ src, const int* __restrict__ dst,
                                const int* __restrict__ row_ptr, const int* __restrict__ cnt,
                                int* __restrict__ cnt2, int* __restrict__ eidx) {
    int i = blockIdx.x * 256 + threadIdx.x;
    if (i < NE) {
        int d = dst[i];
        int p = row_ptr[d] + atomicAdd(&cnt2[d], 1);
        eidx[p] = src[i];
    }
    if (i < NN) {
        int deg = cnt[i], st = row_ptr[i], pd = pad4(deg);
        for (int j = deg; j < pd; ++j) eidx[st + j] = NN;
    }
}

// ---------------- dense pieces ----------------

// Row-blocked dual GEMM: xw = x @ W1 (bf16); res = relu(x @ W2 + rb) (bf16).
// Each wave computes 8 rows x 64 cols; weights packed (w1,w2) in one ds_read_b64,
// reused for 16 FMAs; x broadcast via readlane (SGPR), no LDS traffic.
template <int K>
__global__ __launch_bounds__(256) void gemm_dual_kernel(
    const float* __restrict__ x, const float2* __restrict__ Wpk,
    const float* __restrict__ rb, __hip_bfloat16* __restrict__ xw,
    __hip_bfloat16* __restrict__ res, int n) {
    __shared__ float2 sW[K * HD];
    __shared__ float srb[64];
    for (int i = threadIdx.x; i < K * HD; i += 256) sW[i] = Wpk[i];
    if (threadIdx.x < 64) srb[threadIdx.x] = rb[threadIdx.x];
    __syncthreads();
    int wl = threadIdx.x >> 6, lane = threadIdx.x & 63;
    for (int r0 = (blockIdx.x * 4 + wl) * 8; r0 < n; r0 += gridDim.x * 32) {
        float a1[8], a2[8];
#pragma unroll
        for (int r = 0; r < 8; ++r) { a1[r] = 0.f; a2[r] = 0.f; }
#pragma unroll
        for (int c0 = 0; c0 < K; c0 += 64) {
            const int cl = (K - c0 < 64) ? (K - c0) : 64;
            float xv[8];
#pragma unroll
            for (int r = 0; r < 8; ++r) {
                int row = r0 + r;
                xv[r] = (lane < cl && row < n) ? x[(size_t)row * K + c0 + lane] : 0.f;
            }
            for (int j = 0; j < cl; ++j) {
                float2 w = sW[(c0 + j) * HD + lane];
#pragma unroll
                for (int r = 0; r < 8; ++r) {
                    float xb = __uint_as_float(
                        __builtin_amdgcn_readlane(__float_as_uint(xv[r]), j));
                    a1[r] = fmaf(xb, w.x, a1[r]);
                    a2[r] = fmaf(xb, w.y, a2[r]);
                }
            }
        }
#pragma unroll
        for (int r = 0; r < 8; ++r) {
            int row = r0 + r;
            if (row < n) {
                xw[(size_t)row * HD + lane] = __float2bfloat16(a1[r]);
                res[(size_t)row * HD + lane] = __float2bfloat16(fmaxf(a2[r] + srb[lane], 0.f));
            }
        }
    }
}

// BN fold for layer l>=1: writes packed (Wp,rWp) float2 + shiftW + rbp
__global__ void fold_kernel(const float* __restrict__ stats, const float* __restrict__ g,
                            const float* __restrict__ be, const float* __restrict__ W,
                            const float* __restrict__ rW, const float* __restrict__ rb,
                            float2* __restrict__ Wpk, float* __restrict__ shiftW,
                            float* __restrict__ rbp) {
    __shared__ float sc[64], sh[64];
    int t = threadIdx.x;
    if (t < 64) {
        float mean = stats[t] / (float)NN;
        float var = stats[64 + t] / (float)NN - mean * mean;
        float scale = g[t] * rsqrtf(var + BN_EPS);
        sc[t] = scale;
        sh[t] = be[t] - mean * scale;
    }
    __syncthreads();
    for (int i = t; i < 64 * 64; i += 256) {
        int k = i >> 6;
        Wpk[i] = make_float2(sc[k] * W[i], sc[k] * rW[i]);
    }
    if (t < 64) {
        float sw = 0.f, srw = 0.f;
        for (int k = 0; k < 64; ++k) {
            sw = fmaf(sh[k], W[k * 64 + t], sw);
            srw = fmaf(sh[k], rW[k * 64 + t], srw);
        }
        shiftW[t] = sw;
        rbp[t] = rb[t] + srw;
    }
}

__device__ __forceinline__ float bf_lo(unsigned int p) { return __uint_as_float(p << 16); }
__device__ __forceinline__ float bf_hi(unsigned int p) { return __uint_as_float(p & 0xffff0000u); }

// gather state: 4x 8-B xw loads (16 edges) + res value, per row
struct GState {
    unsigned long long p0, p1, p2, p3;
    unsigned int rv;
    int ng, lo, dg;
};

__device__ __forceinline__ void g_issue(GState& S, int rr, int r0, int rlim,
                                        const int* __restrict__ sRP,
                                        const int* __restrict__ sDeg,
                                        const int* __restrict__ geidx,
                                        const unsigned long long* __restrict__ XWu,
                                        const unsigned short* __restrict__ resu,
                                        int q, int c16, int c) {
    S.p0 = S.p1 = S.p2 = S.p3 = 0ull;
    S.rv = 0u;
    S.ng = 0; S.lo = 0; S.dg = 0;
    if (rr < rlim) {
        int lo = sRP[rr - r0];
        int plen = sRP[rr - r0 + 1] - lo;
        S.lo = lo;
        S.ng = plen >> 2;
        S.dg = sDeg[rr - r0];
        S.rv = resu[(size_t)rr * HD + c];
        if (S.ng > 0) S.p0 = XWu[(size_t)geidx[lo + q] * 16 + c16];
        if (S.ng > 1) S.p1 = XWu[(size_t)geidx[lo + 4 + q] * 16 + c16];
        if (S.ng > 2) S.p2 = XWu[(size_t)geidx[lo + 8 + q] * 16 + c16];
        if (S.ng > 3) S.p3 = XWu[(size_t)geidx[lo + 12 + q] * 16 + c16];
    }
}

__device__ __forceinline__ void g_consume(const GState& S, int rr, int rlim,
                                          const int* __restrict__ geidx,
                                          const unsigned long long* __restrict__ XWu,
                                          const float* __restrict__ sb,
                                          const float* __restrict__ ssw,
                                          float* __restrict__ hout,
                                          int q, int c16, int c,
                                          float& ssum, float& ssum2) {
    if (rr >= rlim) return;
    unsigned l0 = (unsigned)S.p0, h0 = (unsigned)(S.p0 >> 32);
    unsigned l1 = (unsigned)S.p1, h1 = (unsigned)(S.p1 >> 32);
    unsigned l2 = (unsigned)S.p2, h2 = (unsigned)(S.p2 >> 32);
    unsigned l3 = (unsigned)S.p3, h3 = (unsigned)(S.p3 >> 32);
    float a0 = (bf_lo(l0) + bf_lo(l1)) + (bf_lo(l2) + bf_lo(l3));
    float a1 = (bf_hi(l0) + bf_hi(l1)) + (bf_hi(l2) + bf_hi(l3));
    float a2 = (bf_lo(h0) + bf_lo(h1)) + (bf_lo(h2) + bf_lo(h3));
    float a3 = (bf_hi(h0) + bf_hi(h1)) + (bf_hi(h2) + bf_hi(h3));
    for (int k = 4; k < S.ng; ++k) {  // rare: degree > 16
        unsigned long long u = XWu[(size_t)geidx[S.lo + 4 * k + q] * 16 + c16];
        unsigned lo = (unsigned)u, hi = (unsigned)(u >> 32);
        a0 += bf_lo(lo); a1 += bf_hi(lo); a2 += bf_lo(hi); a3 += bf_hi(hi);
    }
    a0 += __shfl_xor(a0, 16, 64); a0 += __shfl_xor(a0, 32, 64);
    a1 += __shfl_xor(a1, 16, 64); a1 += __shfl_xor(a1, 32, 64);
    a2 += __shfl_xor(a2, 16, 64); a2 += __shfl_xor(a2, 32, 64);
    a3 += __shfl_xor(a3, 16, 64); a3 += __shfl_xor(a3, 32, 64);
    float t0 = __shfl(a0, c >> 2, 64);
    float t1 = __shfl(a1, c >> 2, 64);
    float t2 = __shfl(a2, c >> 2, 64);
    float t3 = __shfl(a3, c >> 2, 64);
    float val = (c & 2) ? ((c & 1) ? t3 : t2) : ((c & 1) ? t1 : t0);
    float agg = val + fmaf((float)S.dg, ssw[c], sb[c]);
    float resv = __uint_as_float(S.rv << 16);  // already relu'd in gemm_dual
    float hv = fmaxf(agg, 0.f) + resv;
    hout[(size_t)rr * HD + c] = hv;
    ssum += hv;
    ssum2 += hv * hv;
}

// fused aggregation: h = relu(gather + deg*shiftW + b) + res; stats += (h, h^2)
__global__ __launch_bounds__(256) void fused_agg_kernel(
    const __hip_bfloat16* __restrict__ xw, const __hip_bfloat16* __restrict__ res,
    const float* __restrict__ b, const float* __restrict__ shiftW,
    const int* __restrict__ row_ptr, const int* __restrict__ geidx,
    const int* __restrict__ degs, float* __restrict__ hout, float* __restrict__ stats, int n) {
    __shared__ int sRP[CHUNK + 1];
    __shared__ int sDeg[CHUNK];
    __shared__ float sb[64], ssw[64];
    __shared__ float ls[256], ls2[256];

    int r0 = blockIdx.x * CHUNK;
    int rlim = (r0 + CHUNK < n) ? r0 + CHUNK : n;
    int tid = threadIdx.x;

    if (tid <= CHUNK) {
        int rp = r0 + tid;
        sRP[tid] = row_ptr[(rp < NN) ? rp : NN];
    }
    if (tid >= 64 && tid < 64 + CHUNK) {
        int rp = r0 + (tid - 64);
        sDeg[tid - 64] = (rp < n) ? degs[rp] : 0;
    }
    if (tid >= 128 && tid < 192) {
        sb[tid - 128] = b[tid - 128];
        ssw[tid - 128] = shiftW ? shiftW[tid - 128] : 0.f;
    }
    __syncthreads();

    const unsigned long long* XWu = (const unsigned long long*)xw;
    const unsigned short* resu = (const unsigned short*)res;
    int wl = tid >> 6, c = tid & 63;
    int q = c >> 4;    // edge-quad 0..3
    int c16 = c & 15;  // 8-B chunk of the 128-B row
    float ssum = 0.f, ssum2 = 0.f;
    int rr0 = r0 + wl * 8;

    GState A, B, C, D;
    g_issue(A, rr0 + 0, r0, rlim, sRP, sDeg, geidx, XWu, resu, q, c16, c);
    g_issue(B, rr0 + 1, r0, rlim, sRP, sDeg, geidx, XWu, resu, q, c16, c);
    g_issue(C, rr0 + 2, r0, rlim, sRP, sDeg, geidx, XWu, resu, q, c16, c);
    g_issue(D, rr0 + 3, r0, rlim, sRP, sDeg, geidx, XWu, resu, q, c16, c);
    g_consume(A, rr0 + 0, rlim, geidx, XWu, sb, ssw, hout, q, c16, c, ssum, ssum2);
    g_issue(A, rr0 + 4, r0, rlim, sRP, sDeg, geidx, XWu, resu, q, c16, c);
    g_consume(B, rr0 + 1, rlim, geidx, XWu, sb, ssw, hout, q, c16, c, ssum, ssum2);
    g_issue(B, rr0 + 5, r0, rlim, sRP, sDeg, geidx, XWu, resu, q, c16, c);
    g_consume(C, rr0 + 2, rlim, geidx, XWu, sb, ssw, hout, q, c16, c, ssum, ssum2);
    g_issue(C, rr0 + 6, r0, rlim, sRP, sDeg, geidx, XWu, resu, q, c16, c);
    g_consume(D, rr0 + 3, rlim, geidx, XWu, sb, ssw, hout, q, c16, c, ssum, ssum2);
    g_issue(D, rr0 + 7, r0, rlim, sRP, sDeg, geidx, XWu, resu, q, c16, c);
    g_consume(A, rr0 + 4, rlim, geidx, XWu, sb, ssw, hout, q, c16, c, ssum, ssum2);
    g_consume(B, rr0 + 5, rlim, geidx, XWu, sb, ssw, hout, q, c16, c, ssum, ssum2);
    g_consume(C, rr0 + 6, rlim, geidx, XWu, sb, ssw, hout, q, c16, c, ssum, ssum2);
    g_consume(D, rr0 + 7, rlim, geidx, XWu, sb, ssw, hout, q, c16, c, ssum, ssum2);

    ls[tid] = ssum;
    ls2[tid] = ssum2;
    __syncthreads();
    if (wl == 0) {
        float a = ls[c] + ls[64 + c] + ls[128 + c] + ls[192 + c];
        float a2 = ls2[c] + ls2[64 + c] + ls2[128 + c] + ls2[192 + c];
        atomicAdd(&stats[c], a);
        atomicAdd(&stats[64 + c], a2);
    }
}

// ---------------- readout ----------------

__global__ void readout_init_kernel(float* __restrict__ hsum, unsigned int* __restrict__ hmax,
                                    const float* __restrict__ stats, const float* __restrict__ g,
                                    const float* __restrict__ be, float* __restrict__ ss) {
    int idx = blockIdx.x * 256 + threadIdx.x;
    if (idx < NB * HD) {
        hsum[idx] = 0.f;
        hmax[idx] = 0x007FFFFFu;  // encoded(-inf)
    }
    if (blockIdx.x == 0 && threadIdx.x < 64) {
        int c = threadIdx.x;
        float mean = stats[c] / (float)NN;
        float var = stats[64 + c] / (float)NN - mean * mean;
        float scale = g[c] * rsqrtf(var + BN_EPS);
        ss[c] = scale;
        ss[64 + c] = be[c] - mean * scale;
    }
}

#define RNODES 16

__device__ __forceinline__ void ro_flush(float* hsum, unsigned int* hmax, int g, int c,
                                         float accS, float accM) {
    atomicAdd(&hsum[g * HD + c], accS);
    unsigned int bits = __float_as_uint(accM);
    unsigned int enc = (bits & 0x80000000u) ? ~bits : (bits | 0x80000000u);
    atomicMax(&hmax[g * HD + c], enc);
}

__global__ __launch_bounds__(256) void readout_kernel(
    const float* __restrict__ h, const int* __restrict__ gid, const float* __restrict__ ss,
    const float* __restrict__ awW, const float* __restrict__ awb, float* __restrict__ hsum,
    unsigned int* __restrict__ hmax, int n) {
    int wid = blockIdx.x * 4 + (threadIdx.x >> 6);
    int c = threadIdx.x & 63;
    int r0 = wid * RNODES;
    if (r0 >= n) return;
    int r1 = r0 + RNODES;
    if (r1 > n) r1 = n;
    float aw = awW[c], ab = awb[0];
    float sA = ss[c], sB = ss[64 + c];
    int cur = gid[r0];
    float accS = 0.f, accM = -__builtin_inff();
    for (int r = r0; r < r1; ++r) {
        int g = gid[r];
        if (g != cur) {
            ro_flush(hsum, hmax, cur, c, accS, accM);
            accS = 0.f;
            accM = -__builtin_inff();
            cur = g;
        }
        float v = fmaf(h[(size_t)r * HD + c], sA, sB);
        float p = v * aw;
        for (int off = 32; off; off >>= 1) p += __shfl_xor(p, off, 64);
        float w = 1.f / (1.f + expf(-(p + ab)));
        accS = fmaf(v, w, accS);
        accM = fmaxf(accM, v);
    }
    ro_flush(hsum, hmax, cur, c, accS, accM);
}

__global__ void final_kernel(const float* __restrict__ hsum, const unsigned int* __restrict__ hmax,
                             const float* __restrict__ outW, const float* __restrict__ outb,
                             float* __restrict__ out) {
    __shared__ float sW[128 * 64];
    for (int i = threadIdx.x; i < 128 * 64; i += 256) sW[i] = outW[i];
    __syncthreads();
    int idx = blockIdx.x * 256 + threadIdx.x;
    if (idx >= NB * HD) return;
    int bi = idx >> 6, o = idx & 63;
    float acc = outb[o];
#pragma unroll 4
    for (int k = 0; k < 64; ++k) acc = fmaf(hsum[bi * 64 + k], sW[k * 64 + o], acc);
#pragma unroll 4
    for (int k = 0; k < 64; ++k) {
        unsigned int e = hmax[bi * 64 + k];
        float m;
        if (e == 0x007FFFFFu) {
            m = 0.f;  // empty graph
        } else {
            m = (e & 0x80000000u) ? __uint_as_float(e ^ 0x80000000u) : __uint_as_float(~e);
        }
        acc = fmaf(m, sW[(64 + k) * 64 + o], acc);
    }
    out[idx] = acc;
}

// ---------------- launch ----------------

extern "C" void kernel_launch(void* const* d_in, const int* in_sizes, int n_in,
                              void* d_out, int out_size, void* d_ws, size_t ws_size,
                              hipStream_t stream) {
    const float* feats = (const float*)d_in[0];
    const int* src = (const int*)d_in[1];
    const int* dst = (const int*)d_in[2];
    const int* gid = (const int*)d_in[3];
    const float* W[3];
    const float* b[3];
    const float* rW[3];
    const float* rb[3];
    const float* g[3];
    const float* be[3];
    for (int l = 0; l < 3; ++l) {
        W[l] = (const float*)d_in[4 + 6 * l + 0];
        b[l] = (const float*)d_in[4 + 6 * l + 1];
        rW[l] = (const float*)d_in[4 + 6 * l + 2];
        rb[l] = (const float*)d_in[4 + 6 * l + 3];
        g[l] = (const float*)d_in[4 + 6 * l + 4];
        be[l] = (const float*)d_in[4 + 6 * l + 5];
    }
    const float* awW = (const float*)d_in[22];
    const float* awb = (const float*)d_in[23];
    const float* outW = (const float*)d_in[24];
    const float* outb = (const float*)d_in[25];
    float* out = (float*)d_out;

    // workspace layout
    __hip_bfloat16* XW = (__hip_bfloat16*)d_ws;                 // (NN+1)*64 bf16 (row NN zeros)
    __hip_bfloat16* RES = XW + (size_t)(NN + 1) * HD;           // NN*64 bf16
    float* P1 = (float*)(RES + (size_t)NN * HD);                // N*64 f32 (h, in place)
    float* stats = P1 + (size_t)NN * HD;                        // 3*128
    float* ss2 = stats + 384;                                   // 128
    float2* WPK = (float2*)(ss2 + 128);                         // FIN*HD float2 (9472 floats)
    float* shW = (float*)(WPK + FIN * HD);                      // 64
    float* rbp = shW + 64;                                      // 64
    float* hsum = rbp + 64;                                     // B*64
    unsigned int* hmax = (unsigned int*)(hsum + (size_t)NB * HD);  // B*64
    int* cnt = (int*)(hmax + (size_t)NB * HD);                  // N (real degree)
    int* cnt2 = cnt + NN;                                       // N
    int* row_ptr = cnt2 + NN;                                   // N+1 (padded CSR)
    int* bsum = row_ptr + NN + 1;                               // NCHUNK
    int* eidx = bsum + NCHUNK;                                  // <= NE + 3*NN

    float* stats0 = stats;
    float* stats1 = stats + 128;
    float* stats2 = stats + 256;

    const int EBLK = (NE + 255) / 256;
    const int GEMMBLK = 640;
    const int ROBLK = (NN + RNODES * 4 - 1) / (RNODES * 4);

    // ---- CSR build (padded) + layer-0 weight pack ----
    csr_zero_kernel<<<(NN + 255) / 256, 256, 0, stream>>>(
        cnt, cnt2, stats, (unsigned long long*)(XW + (size_t)NN * HD), W[0], rW[0], WPK);
    csr_hist_kernel<<<EBLK, 256, 0, stream>>>(dst, cnt);
    scanA_kernel<<<NCHUNK, SCHUNK, 0, stream>>>(cnt, bsum);
    scanB_kernel<<<1, 64, 0, stream>>>(bsum);
    scanC_kernel<<<NCHUNK, SCHUNK, 0, stream>>>(cnt, bsum, row_ptr);
    csr_fill_kernel<<<EBLK, 256, 0, stream>>>(src, dst, row_ptr, cnt, cnt2, eidx);

    // ---- layer 0 ----
    gemm_dual_kernel<FIN><<<GEMMBLK, 256, 0, stream>>>(feats, WPK, rb[0], XW, RES, NN);
    fused_agg_kernel<<<NBLK, 256, 0, stream>>>(XW, RES, b[0], (const float*)nullptr, row_ptr,
                                               eidx, cnt, P1, stats0, NN);

    // ---- layer 1 (fold BN0) ----
    fold_kernel<<<1, 256, 0, stream>>>(stats0, g[0], be[0], W[1], rW[1], rb[1], WPK, shW, rbp);
    gemm_dual_kernel<HD><<<GEMMBLK, 256, 0, stream>>>(P1, WPK, rbp, XW, RES, NN);
    fused_agg_kernel<<<NBLK, 256, 0, stream>>>(XW, RES, b[1], shW, row_ptr, eidx, cnt, P1,
                                               stats1, NN);

    // ---- layer 2 (fold BN1) ----
    fold_kernel<<<1, 256, 0, stream>>>(stats1, g[1], be[1], W[2], rW[2], rb[2], WPK, shW, rbp);
    gemm_dual_kernel<HD><<<GEMMBLK, 256, 0, stream>>>(P1, WPK, rbp, XW, RES, NN);
    fused_agg_kernel<<<NBLK, 256, 0, stream>>>(XW, RES, b[2], shW, row_ptr, eidx, cnt, P1,
                                               stats2, NN);

    // ---- readout (BN2 on the fly) ----
    readout_init_kernel<<<(NB * HD + 255) / 256, 256, 0, stream>>>(hsum, hmax, stats2, g[2], be[2], ss2);
    readout_kernel<<<ROBLK, 256, 0, stream>>>(P1, gid, ss2, awW, awb, hsum, hmax, NN);
    final_kernel<<<(NB * HD + 255) / 256, 256, 0, stream>>>(hsum, hmax, outW, outb, out);
}

// Round 8
// 389.183 us; speedup vs baseline: 1.3650x; 1.1551x over previous
//
#include <hip/hip_runtime.h>
#include <hip/hip_bf16.h>
#include <math.h>

#define NN 50000
#define NE 800000
#define NB 512
#define FIN 74
#define HD 64
#define BN_EPS 1e-5f

#define SCHUNK 512
#define NCHUNK ((NN + SCHUNK - 1) / SCHUNK)  // 98

#define CHUNK 32
#define ELLW 32
#define NBLK ((NN + CHUNK - 1) / CHUNK)  // 1563

// ---------------- CSR build ----------------

// also packs layer-0 weights into (W,rW) float2 pairs
__global__ void csr_zero_kernel(int* __restrict__ cnt, int* __restrict__ cnt2,
                                float* __restrict__ stats012,
                                unsigned long long* __restrict__ xw_zrow,
                                const float* __restrict__ W0, const float* __restrict__ rW0,
                                float2* __restrict__ Wpk0) {
    int i = blockIdx.x * 256 + threadIdx.x;
    if (i < NN) { cnt[i] = 0; cnt2[i] = 0; }
    if (i < 384) stats012[i] = 0.f;
    if (i < 16) xw_zrow[i] = 0ull;  // XW row NN = 128 B of zeros
    if (i < FIN * HD) Wpk0[i] = make_float2(W0[i], rW0[i]);
}

__global__ void csr_hist_kernel(const int* __restrict__ dst, int* __restrict__ cnt) {
    int e = blockIdx.x * 256 + threadIdx.x;
    if (e < NE) atomicAdd(&cnt[dst[e]], 1);
}

__global__ void scanA_kernel(const int* __restrict__ cnt, int* __restrict__ bsum) {
    __shared__ int l[SCHUNK];
    int i = blockIdx.x * SCHUNK + threadIdx.x;
    int v = (i < NN) ? cnt[i] : 0;
    l[threadIdx.x] = v;
    __syncthreads();
    for (int off = SCHUNK / 2; off; off >>= 1) {
        if (threadIdx.x < off) l[threadIdx.x] += l[threadIdx.x + off];
        __syncthreads();
    }
    if (threadIdx.x == 0) bsum[blockIdx.x] = l[0];
}

__global__ void scanB_kernel(int* __restrict__ bsum) {
    int lane = threadIdx.x;  // 64 threads
    int v0 = (lane < NCHUNK) ? bsum[lane] : 0;
    int v1 = (64 + lane < NCHUNK) ? bsum[64 + lane] : 0;
    int s0 = v0, s1 = v1;
    for (int off = 1; off < 64; off <<= 1) {
        int t0 = __shfl_up(s0, off, 64);
        int t1 = __shfl_up(s1, off, 64);
        if (lane >= off) { s0 += t0; s1 += t1; }
    }
    int tot0 = __shfl(s0, 63, 64);
    if (lane < NCHUNK) bsum[lane] = s0 - v0;
    if (64 + lane < NCHUNK) bsum[64 + lane] = s1 - v1 + tot0;
}

__global__ void scanC_kernel(const int* __restrict__ cnt, const int* __restrict__ bsum,
                             int* __restrict__ row_ptr) {
    __shared__ int l[SCHUNK];
    int i = blockIdx.x * SCHUNK + threadIdx.x;
    int v = (i < NN) ? cnt[i] : 0;
    l[threadIdx.x] = v;
    __syncthreads();
    for (int off = 1; off < SCHUNK; off <<= 1) {
        int t = (threadIdx.x >= off) ? l[threadIdx.x - off] : 0;
        __syncthreads();
        l[threadIdx.x] += t;
        __syncthreads();
    }
    int excl = l[threadIdx.x] - v + bsum[blockIdx.x];
    if (i < NN) row_ptr[i] = excl;
    if (i == NN - 1) row_ptr[NN] = excl + v;
}

__global__ void csr_fill_kernel(const int* __restrict__ src, const int* __restrict__ dst,
                                const int* __restrict__ row_ptr, int* __restrict__ cnt2,
                                int* __restrict__ eidx) {
    int i = blockIdx.x * 256 + threadIdx.x;
    if (i < NE) {
        int d = dst[i];
        int p = row_ptr[d] + atomicAdd(&cnt2[d], 1);
        eidx[p] = src[i];
    }
}

// ---------------- dense pieces ----------------

// Row-blocked dual GEMM: xw = x @ W1 (bf16); res = relu(x @ W2 + rb) (bf16).
template <int K>
__global__ __launch_bounds__(256) void gemm_dual_kernel(
    const float* __restrict__ x, const float2* __restrict__ Wpk,
    const float* __restrict__ rb, __hip_bfloat16* __restrict__ xw,
    __hip_bfloat16* __restrict__ res, int n) {
    __shared__ float2 sW[K * HD];
    __shared__ float srb[64];
    for (int i = threadIdx.x; i < K * HD; i += 256) sW[i] = Wpk[i];
    if (threadIdx.x < 64) srb[threadIdx.x] = rb[threadIdx.x];
    __syncthreads();
    int wl = threadIdx.x >> 6, lane = threadIdx.x & 63;
    for (int r0 = (blockIdx.x * 4 + wl) * 8; r0 < n; r0 += gridDim.x * 32) {
        float a1[8], a2[8];
#pragma unroll
        for (int r = 0; r < 8; ++r) { a1[r] = 0.f; a2[r] = 0.f; }
#pragma unroll
        for (int c0 = 0; c0 < K; c0 += 64) {
            const int cl = (K - c0 < 64) ? (K - c0) : 64;
            float xv[8];
#pragma unroll
            for (int r = 0; r < 8; ++r) {
                int row = r0 + r;
                xv[r] = (lane < cl && row < n) ? x[(size_t)row * K + c0 + lane] : 0.f;
            }
            for (int j = 0; j < cl; ++j) {
                float2 w = sW[(c0 + j) * HD + lane];
#pragma unroll
                for (int r = 0; r < 8; ++r) {
                    float xb = __uint_as_float(
                        __builtin_amdgcn_readlane(__float_as_uint(xv[r]), j));
                    a1[r] = fmaf(xb, w.x, a1[r]);
                    a2[r] = fmaf(xb, w.y, a2[r]);
                }
            }
        }
#pragma unroll
        for (int r = 0; r < 8; ++r) {
            int row = r0 + r;
            if (row < n) {
                xw[(size_t)row * HD + lane] = __float2bfloat16(a1[r]);
                res[(size_t)row * HD + lane] = __float2bfloat16(fmaxf(a2[r] + srb[lane], 0.f));
            }
        }
    }
}

// BN fold for layer l>=1: writes packed (Wp,rWp) float2 + shiftW + rbp
__global__ void fold_kernel(const float* __restrict__ stats, const float* __restrict__ g,
                            const float* __restrict__ be, const float* __restrict__ W,
                            const float* __restrict__ rW, const float* __restrict__ rb,
                            float2* __restrict__ Wpk, float* __restrict__ shiftW,
                            float* __restrict__ rbp) {
    __shared__ float sc[64], sh[64];
    int t = threadIdx.x;
    if (t < 64) {
        float mean = stats[t] / (float)NN;
        float var = stats[64 + t] / (float)NN - mean * mean;
        float scale = g[t] * rsqrtf(var + BN_EPS);
        sc[t] = scale;
        sh[t] = be[t] - mean * scale;
    }
    __syncthreads();
    for (int i = t; i < 64 * 64; i += 256) {
        int k = i >> 6;
        Wpk[i] = make_float2(sc[k] * W[i], sc[k] * rW[i]);
    }
    if (t < 64) {
        float sw = 0.f, srw = 0.f;
        for (int k = 0; k < 64; ++k) {
            sw = fmaf(sh[k], W[k * 64 + t], sw);
            srw = fmaf(sh[k], rW[k * 64 + t], srw);
        }
        shiftW[t] = sw;
        rbp[t] = rb[t] + srw;
    }
}

__device__ __forceinline__ float bf_lo(unsigned int p) { return __uint_as_float(p << 16); }
__device__ __forceinline__ float bf_hi(unsigned int p) { return __uint_as_float(p & 0xffff0000u); }

// fused aggregation v3: lane = dword-column, 2 rows per wave-step, ELL-32 LDS idx.
// h = relu(gather + deg*shiftW + b) + res; stats += (h, h^2). No cross-lane ops.
__global__ __launch_bounds__(256) void fused_agg_kernel(
    const __hip_bfloat16* __restrict__ xw, const __hip_bfloat16* __restrict__ res,
    const float* __restrict__ b, const float* __restrict__ shiftW,
    const int* __restrict__ row_ptr, const int* __restrict__ geidx,
    float* __restrict__ hout, float* __restrict__ stats, int n) {
    __shared__ int sIdx[CHUNK][ELLW];  // 4 KB, NN-padded
    __shared__ int sRP[CHUNK + 1];
    __shared__ int sLen[CHUNK];
    __shared__ float sbb[128];  // b | shiftW
    __shared__ float lsr[256 * 4];

    int tid = threadIdx.x;
    int r0 = blockIdx.x * CHUNK;

    if (tid <= CHUNK) {
        int rp = r0 + tid;
        sRP[tid] = row_ptr[(rp < NN) ? rp : NN];
    }
    if (tid >= 128 && tid < 256) {
        int j = tid - 128;
        sbb[j] = (j < 64) ? b[j] : (shiftW ? shiftW[j - 64] : 0.f);
    }
    __syncthreads();
    for (int i = tid; i < CHUNK * ELLW; i += 256) {
        int r = i >> 5, j = i & 31;
        int beg = sRP[r];
        int plen = sRP[r + 1] - beg;
        sIdx[r][j] = (j < plen) ? geidx[beg + j] : NN;
        if (j == 0) sLen[r] = plen;
    }
    __syncthreads();

    const unsigned* XWdw = (const unsigned*)xw;
    const unsigned* REdw = (const unsigned*)res;
    int wl = tid >> 6, lane = tid & 63;
    int c2 = lane & 31, half = lane >> 5;
    float sb0 = sbb[2 * c2], sb1 = sbb[2 * c2 + 1];
    float sw0 = sbb[64 + 2 * c2], sw1 = sbb[64 + 2 * c2 + 1];
    float s0 = 0.f, s1 = 0.f, q0 = 0.f, q1 = 0.f;

#pragma unroll
    for (int p = 0; p < 4; ++p) {
        int rA = wl * 8 + 2 * p;       // local row pair
        int rloc = rA + half;          // my local row
        int grow = r0 + rloc;          // my global row
        int growc = (grow < n) ? grow : (n - 1);
        int lenA = sLen[rA], lenB = sLen[rA + 1];
        int kmax = (lenA > lenB) ? lenA : lenB;  // wave-uniform
        int mylen = half ? lenB : lenA;
        unsigned rdw = REdw[(size_t)growc * 32 + c2];  // residual, issued early
        float a0 = 0.f, a1 = 0.f;
        int klim = (kmax < ELLW) ? kmax : ELLW;
        for (int k8 = 0; k8 < klim; k8 += 8) {  // uniform branch
#pragma unroll
            for (int j = 0; j < 8; ++j) {
                int idx = sIdx[rloc][k8 + j];  // NN-padded -> always safe
                unsigned dw = XWdw[(size_t)idx * 32 + c2];
                a0 += bf_lo(dw);
                a1 += bf_hi(dw);
            }
        }
        if (kmax > ELLW) {  // rare (deg > 32), uniform
            int beg = sRP[rloc];
            for (int k = ELLW; k < kmax; ++k) {
                int idx = geidx[beg + k];  // slack-padded array; value select below
                unsigned dw = XWdw[(size_t)((k < mylen) ? idx : NN) * 32 + c2];
                a0 += bf_lo(dw);
                a1 += bf_hi(dw);
            }
        }
        float dg = (float)mylen;
        float hv0 = fmaxf(a0 + fmaf(dg, sw0, sb0), 0.f) + bf_lo(rdw);
        float hv1 = fmaxf(a1 + fmaf(dg, sw1, sb1), 0.f) + bf_hi(rdw);
        if (grow < n) {
            *(float2*)&hout[(size_t)grow * HD + 2 * c2] = make_float2(hv0, hv1);
            s0 += hv0; s1 += hv1;
            q0 += hv0 * hv0; q1 += hv1 * hv1;
        }
    }

    lsr[tid * 4 + 0] = s0;
    lsr[tid * 4 + 1] = s1;
    lsr[tid * 4 + 2] = q0;
    lsr[tid * 4 + 3] = q1;
    __syncthreads();
    if (tid < 64) {
        int comp = tid & 1, c2i = tid >> 1;
        float ss = 0.f, qq = 0.f;
#pragma unroll
        for (int w = 0; w < 4; ++w)
#pragma unroll
            for (int h = 0; h < 2; ++h) {
                int t = w * 64 + h * 32 + c2i;
                ss += lsr[t * 4 + comp];
                qq += lsr[t * 4 + 2 + comp];
            }
        atomicAdd(&stats[tid], ss);
        atomicAdd(&stats[64 + tid], qq);
    }
}

// ---------------- readout ----------------

__global__ void readout_init_kernel(float* __restrict__ hsum, unsigned int* __restrict__ hmax,
                                    const float* __restrict__ stats, const float* __restrict__ g,
                                    const float* __restrict__ be, float* __restrict__ ss) {
    int idx = blockIdx.x * 256 + threadIdx.x;
    if (idx < NB * HD) {
        hsum[idx] = 0.f;
        hmax[idx] = 0x007FFFFFu;  // encoded(-inf)
    }
    if (blockIdx.x == 0 && threadIdx.x < 64) {
        int c = threadIdx.x;
        float mean = stats[c] / (float)NN;
        float var = stats[64 + c] / (float)NN - mean * mean;
        float scale = g[c] * rsqrtf(var + BN_EPS);
        ss[c] = scale;
        ss[64 + c] = be[c] - mean * scale;
    }
}

#define RNODES 16

__device__ __forceinline__ void ro_flush(float* hsum, unsigned int* hmax, int g, int c,
                                         float accS, float accM) {
    atomicAdd(&hsum[g * HD + c], accS);
    unsigned int bits = __float_as_uint(accM);
    unsigned int enc = (bits & 0x80000000u) ? ~bits : (bits | 0x80000000u);
    atomicMax(&hmax[g * HD + c], enc);
}

__global__ __launch_bounds__(256) void readout_kernel(
    const float* __restrict__ h, const int* __restrict__ gid, const float* __restrict__ ss,
    const float* __restrict__ awW, const float* __restrict__ awb, float* __restrict__ hsum,
    unsigned int* __restrict__ hmax, int n) {
    int wid = blockIdx.x * 4 + (threadIdx.x >> 6);
    int c = threadIdx.x & 63;
    int r0 = wid * RNODES;
    if (r0 >= n) return;
    int r1 = r0 + RNODES;
    if (r1 > n) r1 = n;
    float aw = awW[c], ab = awb[0];
    float sA = ss[c], sB = ss[64 + c];
    int cur = gid[r0];
    float accS = 0.f, accM = -__builtin_inff();
    for (int r = r0; r < r1; ++r) {
        int g = gid[r];
        if (g != cur) {
            ro_flush(hsum, hmax, cur, c, accS, accM);
            accS = 0.f;
            accM = -__builtin_inff();
            cur = g;
        }
        float v = fmaf(h[(size_t)r * HD + c], sA, sB);
        float p = v * aw;
        for (int off = 32; off; off >>= 1) p += __shfl_xor(p, off, 64);
        float w = 1.f / (1.f + expf(-(p + ab)));
        accS = fmaf(v, w, accS);
        accM = fmaxf(accM, v);
    }
    ro_flush(hsum, hmax, cur, c, accS, accM);
}

__global__ void final_kernel(const float* __restrict__ hsum, const unsigned int* __restrict__ hmax,
                             const float* __restrict__ outW, const float* __restrict__ outb,
                             float* __restrict__ out) {
    __shared__ float sW[128 * 64];
    for (int i = threadIdx.x; i < 128 * 64; i += 256) sW[i] = outW[i];
    __syncthreads();
    int idx = blockIdx.x * 256 + threadIdx.x;
    if (idx >= NB * HD) return;
    int bi = idx >> 6, o = idx & 63;
    float acc = outb[o];
#pragma unroll 4
    for (int k = 0; k < 64; ++k) acc = fmaf(hsum[bi * 64 + k], sW[k * 64 + o], acc);
#pragma unroll 4
    for (int k = 0; k < 64; ++k) {
        unsigned int e = hmax[bi * 64 + k];
        float m;
        if (e == 0x007FFFFFu) {
            m = 0.f;  // empty graph
        } else {
            m = (e & 0x80000000u) ? __uint_as_float(e ^ 0x80000000u) : __uint_as_float(~e);
        }
        acc = fmaf(m, sW[(64 + k) * 64 + o], acc);
    }
    out[idx] = acc;
}

// ---------------- launch ----------------

extern "C" void kernel_launch(void* const* d_in, const int* in_sizes, int n_in,
                              void* d_out, int out_size, void* d_ws, size_t ws_size,
                              hipStream_t stream) {
    const float* feats = (const float*)d_in[0];
    const int* src = (const int*)d_in[1];
    const int* dst = (const int*)d_in[2];
    const int* gid = (const int*)d_in[3];
    const float* W[3];
    const float* b[3];
    const float* rW[3];
    const float* rb[3];
    const float* g[3];
    const float* be[3];
    for (int l = 0; l < 3; ++l) {
        W[l] = (const float*)d_in[4 + 6 * l + 0];
        b[l] = (const float*)d_in[4 + 6 * l + 1];
        rW[l] = (const float*)d_in[4 + 6 * l + 2];
        rb[l] = (const float*)d_in[4 + 6 * l + 3];
        g[l] = (const float*)d_in[4 + 6 * l + 4];
        be[l] = (const float*)d_in[4 + 6 * l + 5];
    }
    const float* awW = (const float*)d_in[22];
    const float* awb = (const float*)d_in[23];
    const float* outW = (const float*)d_in[24];
    const float* outb = (const float*)d_in[25];
    float* out = (float*)d_out;

    // workspace layout
    __hip_bfloat16* XW = (__hip_bfloat16*)d_ws;                 // (NN+1)*64 bf16 (row NN zeros)
    __hip_bfloat16* RES = XW + (size_t)(NN + 1) * HD;           // NN*64 bf16
    float* P1 = (float*)(RES + (size_t)NN * HD);                // N*64 f32 (h, in place)
    float* stats = P1 + (size_t)NN * HD;                        // 3*128
    float* ss2 = stats + 384;                                   // 128
    float2* WPK = (float2*)(ss2 + 128);                         // FIN*HD float2
    float* shW = (float*)(WPK + FIN * HD);                      // 64
    float* rbp = shW + 64;                                      // 64
    float* hsum = rbp + 64;                                     // B*64
    unsigned int* hmax = (unsigned int*)(hsum + (size_t)NB * HD);  // B*64
    int* cnt = (int*)(hmax + (size_t)NB * HD);                  // N
    int* cnt2 = cnt + NN;                                       // N
    int* row_ptr = cnt2 + NN;                                   // N+1
    int* bsum = row_ptr + NN + 1;                               // NCHUNK
    int* eidx = bsum + NCHUNK;                                  // NE + 64 slack

    float* stats0 = stats;
    float* stats1 = stats + 128;
    float* stats2 = stats + 256;

    const int EBLK = (NE + 255) / 256;
    const int GEMMBLK = 640;
    const int ROBLK = (NN + RNODES * 4 - 1) / (RNODES * 4);

    // ---- CSR build + layer-0 weight pack ----
    csr_zero_kernel<<<(NN + 255) / 256, 256, 0, stream>>>(
        cnt, cnt2, stats, (unsigned long long*)(XW + (size_t)NN * HD), W[0], rW[0], WPK);
    csr_hist_kernel<<<EBLK, 256, 0, stream>>>(dst, cnt);
    scanA_kernel<<<NCHUNK, SCHUNK, 0, stream>>>(cnt, bsum);
    scanB_kernel<<<1, 64, 0, stream>>>(bsum);
    scanC_kernel<<<NCHUNK, SCHUNK, 0, stream>>>(cnt, bsum, row_ptr);
    csr_fill_kernel<<<EBLK, 256, 0, stream>>>(src, dst, row_ptr, cnt2, eidx);

    // ---- layer 0 ----
    gemm_dual_kernel<FIN><<<GEMMBLK, 256, 0, stream>>>(feats, WPK, rb[0], XW, RES, NN);
    fused_agg_kernel<<<NBLK, 256, 0, stream>>>(XW, RES, b[0], (const float*)nullptr, row_ptr,
                                               eidx, P1, stats0, NN);

    // ---- layer 1 (fold BN0) ----
    fold_kernel<<<1, 256, 0, stream>>>(stats0, g[0], be[0], W[1], rW[1], rb[1], WPK, shW, rbp);
    gemm_dual_kernel<HD><<<GEMMBLK, 256, 0, stream>>>(P1, WPK, rbp, XW, RES, NN);
    fused_agg_kernel<<<NBLK, 256, 0, stream>>>(XW, RES, b[1], shW, row_ptr, eidx, P1, stats1, NN);

    // ---- layer 2 (fold BN1) ----
    fold_kernel<<<1, 256, 0, stream>>>(stats1, g[1], be[1], W[2], rW[2], rb[2], WPK, shW, rbp);
    gemm_dual_kernel<HD><<<GEMMBLK, 256, 0, stream>>>(P1, WPK, rbp, XW, RES, NN);
    fused_agg_kernel<<<NBLK, 256, 0, stream>>>(XW, RES, b[2], shW, row_ptr, eidx, P1, stats2, NN);

    // ---- readout (BN2 on the fly) ----
    readout_init_kernel<<<(NB * HD + 255) / 256, 256, 0, stream>>>(hsum, hmax, stats2, g[2], be[2], ss2);
    readout_kernel<<<ROBLK, 256, 0, stream>>>(P1, gid, ss2, awW, awb, hsum, hmax, NN);
    final_kernel<<<(NB * HD + 255) / 256, 256, 0, stream>>>(hsum, hmax, outW, outb, out);
}

// Round 9
// 371.231 us; speedup vs baseline: 1.4310x; 1.0484x over previous
//
#include <hip/hip_runtime.h>
#include <hip/hip_bf16.h>
#include <math.h>

#define NN 50000
#define NE 800000
#define NB 512
#define FIN 74
#define HD 64
#define BN_EPS 1e-5f

#define SCHUNK 512
#define NCHUNK ((NN + SCHUNK - 1) / SCHUNK)  // 98

#define CHUNK 32
#define ELLW 32
#define NBLK ((NN + CHUNK - 1) / CHUNK)  // 1563

// ---------------- CSR build ----------------

// also packs layer-0 weights into (W,rW) float2 pairs
__global__ void csr_zero_kernel(int* __restrict__ cnt, int* __restrict__ cnt2,
                                float* __restrict__ stats012,
                                unsigned long long* __restrict__ xw_zrow,
                                const float* __restrict__ W0, const float* __restrict__ rW0,
                                float2* __restrict__ Wpk0) {
    int i = blockIdx.x * 256 + threadIdx.x;
    if (i < NN) { cnt[i] = 0; cnt2[i] = 0; }
    if (i < 384) stats012[i] = 0.f;
    if (i < 16) xw_zrow[i] = 0ull;  // XW row NN = 128 B of zeros
    if (i < FIN * HD) Wpk0[i] = make_float2(W0[i], rW0[i]);
}

__global__ void csr_hist_kernel(const int* __restrict__ dst, int* __restrict__ cnt) {
    int e = blockIdx.x * 256 + threadIdx.x;
    if (e < NE) atomicAdd(&cnt[dst[e]], 1);
}

__global__ void scanA_kernel(const int* __restrict__ cnt, int* __restrict__ bsum) {
    __shared__ int l[SCHUNK];
    int i = blockIdx.x * SCHUNK + threadIdx.x;
    int v = (i < NN) ? cnt[i] : 0;
    l[threadIdx.x] = v;
    __syncthreads();
    for (int off = SCHUNK / 2; off; off >>= 1) {
        if (threadIdx.x < off) l[threadIdx.x] += l[threadIdx.x + off];
        __syncthreads();
    }
    if (threadIdx.x == 0) bsum[blockIdx.x] = l[0];
}

__global__ void scanB_kernel(int* __restrict__ bsum) {
    int lane = threadIdx.x;  // 64 threads
    int v0 = (lane < NCHUNK) ? bsum[lane] : 0;
    int v1 = (64 + lane < NCHUNK) ? bsum[64 + lane] : 0;
    int s0 = v0, s1 = v1;
    for (int off = 1; off < 64; off <<= 1) {
        int t0 = __shfl_up(s0, off, 64);
        int t1 = __shfl_up(s1, off, 64);
        if (lane >= off) { s0 += t0; s1 += t1; }
    }
    int tot0 = __shfl(s0, 63, 64);
    if (lane < NCHUNK) bsum[lane] = s0 - v0;
    if (64 + lane < NCHUNK) bsum[64 + lane] = s1 - v1 + tot0;
}

__global__ void scanC_kernel(const int* __restrict__ cnt, const int* __restrict__ bsum,
                             int* __restrict__ row_ptr) {
    __shared__ int l[SCHUNK];
    int i = blockIdx.x * SCHUNK + threadIdx.x;
    int v = (i < NN) ? cnt[i] : 0;
    l[threadIdx.x] = v;
    __syncthreads();
    for (int off = 1; off < SCHUNK; off <<= 1) {
        int t = (threadIdx.x >= off) ? l[threadIdx.x - off] : 0;
        __syncthreads();
        l[threadIdx.x] += t;
        __syncthreads();
    }
    int excl = l[threadIdx.x] - v + bsum[blockIdx.x];
    if (i < NN) row_ptr[i] = excl;
    if (i == NN - 1) row_ptr[NN] = excl + v;
}

__global__ void csr_fill_kernel(const int* __restrict__ src, const int* __restrict__ dst,
                                const int* __restrict__ row_ptr, int* __restrict__ cnt2,
                                int* __restrict__ eidx) {
    int i = blockIdx.x * 256 + threadIdx.x;
    if (i < NE) {
        int d = dst[i];
        int p = row_ptr[d] + atomicAdd(&cnt2[d], 1);
        eidx[p] = src[i];
    }
}

// ---------------- dense pieces ----------------

// Row-blocked dual GEMM: xw = x @ W1 (bf16); res = relu(x @ W2 + rb) (bf16).
template <int K>
__global__ __launch_bounds__(256) void gemm_dual_kernel(
    const float* __restrict__ x, const float2* __restrict__ Wpk,
    const float* __restrict__ rb, __hip_bfloat16* __restrict__ xw,
    __hip_bfloat16* __restrict__ res, int n) {
    __shared__ float2 sW[K * HD];
    __shared__ float srb[64];
    for (int i = threadIdx.x; i < K * HD; i += 256) sW[i] = Wpk[i];
    if (threadIdx.x < 64) srb[threadIdx.x] = rb[threadIdx.x];
    __syncthreads();
    int wl = threadIdx.x >> 6, lane = threadIdx.x & 63;
    for (int r0 = (blockIdx.x * 4 + wl) * 8; r0 < n; r0 += gridDim.x * 32) {
        float a1[8], a2[8];
#pragma unroll
        for (int r = 0; r < 8; ++r) { a1[r] = 0.f; a2[r] = 0.f; }
#pragma unroll
        for (int c0 = 0; c0 < K; c0 += 64) {
            const int cl = (K - c0 < 64) ? (K - c0) : 64;
            float xv[8];
#pragma unroll
            for (int r = 0; r < 8; ++r) {
                int row = r0 + r;
                xv[r] = (lane < cl && row < n) ? x[(size_t)row * K + c0 + lane] : 0.f;
            }
            for (int j = 0; j < cl; ++j) {
                float2 w = sW[(c0 + j) * HD + lane];
#pragma unroll
                for (int r = 0; r < 8; ++r) {
                    float xb = __uint_as_float(
                        __builtin_amdgcn_readlane(__float_as_uint(xv[r]), j));
                    a1[r] = fmaf(xb, w.x, a1[r]);
                    a2[r] = fmaf(xb, w.y, a2[r]);
                }
            }
        }
#pragma unroll
        for (int r = 0; r < 8; ++r) {
            int row = r0 + r;
            if (row < n) {
                xw[(size_t)row * HD + lane] = __float2bfloat16(a1[r]);
                res[(size_t)row * HD + lane] = __float2bfloat16(fmaxf(a2[r] + srb[lane], 0.f));
            }
        }
    }
}

// BN fold for layer l>=1: writes packed (Wp,rWp) float2 + shiftW + rbp
__global__ void fold_kernel(const float* __restrict__ stats, const float* __restrict__ g,
                            const float* __restrict__ be, const float* __restrict__ W,
                            const float* __restrict__ rW, const float* __restrict__ rb,
                            float2* __restrict__ Wpk, float* __restrict__ shiftW,
                            float* __restrict__ rbp) {
    __shared__ float sc[64], sh[64];
    int t = threadIdx.x;
    if (t < 64) {
        float mean = stats[t] / (float)NN;
        float var = stats[64 + t] / (float)NN - mean * mean;
        float scale = g[t] * rsqrtf(var + BN_EPS);
        sc[t] = scale;
        sh[t] = be[t] - mean * scale;
    }
    __syncthreads();
    for (int i = t; i < 64 * 64; i += 256) {
        int k = i >> 6;
        Wpk[i] = make_float2(sc[k] * W[i], sc[k] * rW[i]);
    }
    if (t < 64) {
        float sw = 0.f, srw = 0.f;
        for (int k = 0; k < 64; ++k) {
            sw = fmaf(sh[k], W[k * 64 + t], sw);
            srw = fmaf(sh[k], rW[k * 64 + t], srw);
        }
        shiftW[t] = sw;
        rbp[t] = rb[t] + srw;
    }
}

__device__ __forceinline__ float bf_lo(unsigned int p) { return __uint_as_float(p << 16); }
__device__ __forceinline__ float bf_hi(unsigned int p) { return __uint_as_float(p & 0xffff0000u); }

// 16-slot branch-free gather batch (pads hit the hot zero row -> L1)
#define GATHER16(BASE)                                             \
    {                                                              \
        unsigned long long d[16];                                  \
        _Pragma("unroll") for (int j = 0; j < 16; ++j) {           \
            int idx = sIdx[rloc][(BASE) + j];                      \
            unsigned off = (unsigned)idx * 16u + (unsigned)c8;     \
            d[j] = XWu[off];                                       \
        }                                                          \
        _Pragma("unroll") for (int j = 0; j < 16; ++j) {           \
            unsigned lo = (unsigned)d[j], hi = (unsigned)(d[j] >> 32); \
            a0 += bf_lo(lo); a1 += bf_hi(lo);                      \
            a2 += bf_lo(hi); a3 += bf_hi(hi);                      \
        }                                                          \
    }

// fused aggregation v4: 16 lanes/row (8-B loads), 4 rows in flight per wave step,
// fixed-16 branch-free phases. h = relu(gather + deg*shiftW + b) + res; stats += (h,h^2).
__global__ __launch_bounds__(256, 4) void fused_agg_kernel(
    const __hip_bfloat16* __restrict__ xw, const __hip_bfloat16* __restrict__ res,
    const float* __restrict__ b, const float* __restrict__ shiftW,
    const int* __restrict__ row_ptr, const int* __restrict__ geidx,
    float* __restrict__ hout, float* __restrict__ stats, int n) {
    __shared__ int sIdx[CHUNK][ELLW + 1];  // +1 pad: spread quarter broadcasts over banks
    __shared__ int sRP[CHUNK + 1];
    __shared__ int sLen[CHUNK];
    __shared__ float sbb[128];          // b | shiftW
    __shared__ float lsr[4][16][8];     // wave x c8 x {4 sums, 4 sumsqs}

    int tid = threadIdx.x;
    int r0 = blockIdx.x * CHUNK;

    if (tid <= CHUNK) {
        int rp = r0 + tid;
        sRP[tid] = row_ptr[(rp < NN) ? rp : NN];
    }
    if (tid >= 128 && tid < 256) {
        int j = tid - 128;
        sbb[j] = (j < 64) ? b[j] : (shiftW ? shiftW[j - 64] : 0.f);
    }
    __syncthreads();
    for (int i = tid; i < CHUNK * ELLW; i += 256) {
        int r = i >> 5, j = i & 31;
        int beg = sRP[r];
        int plen = sRP[r + 1] - beg;
        sIdx[r][j] = (j < plen) ? geidx[beg + j] : NN;
        if (j == 0) sLen[r] = plen;
    }
    __syncthreads();

    const unsigned long long* XWu = (const unsigned long long*)xw;
    const unsigned long long* REu = (const unsigned long long*)res;
    int wl = tid >> 6, lane = tid & 63;
    int q = lane >> 4, c8 = lane & 15;
    float sb0 = sbb[4 * c8], sb1 = sbb[4 * c8 + 1], sb2 = sbb[4 * c8 + 2], sb3 = sbb[4 * c8 + 3];
    float sw0 = sbb[64 + 4 * c8], sw1 = sbb[64 + 4 * c8 + 1];
    float sw2 = sbb[64 + 4 * c8 + 2], sw3 = sbb[64 + 4 * c8 + 3];
    float s0 = 0.f, s1 = 0.f, s2 = 0.f, s3 = 0.f;
    float q0 = 0.f, q1 = 0.f, q2 = 0.f, q3 = 0.f;

#pragma unroll
    for (int p = 0; p < 2; ++p) {
        int rbase = wl * 8 + p * 4;
        int rloc = rbase + q;
        int grow = r0 + rloc;
        int growc = (grow < n) ? grow : (n - 1);
        int l0 = sLen[rbase], l1 = sLen[rbase + 1], l2 = sLen[rbase + 2], l3 = sLen[rbase + 3];
        int m01 = (l0 > l1) ? l0 : l1, m23 = (l2 > l3) ? l2 : l3;
        int kmax = (m01 > m23) ? m01 : m23;  // wave-uniform
        int mylen = sLen[rloc];
        unsigned long long rqw = REu[(unsigned)growc * 16u + (unsigned)c8];  // residual early
        float a0 = 0.f, a1 = 0.f, a2 = 0.f, a3 = 0.f;
        GATHER16(0)
        if (kmax > 16) GATHER16(16)
        if (kmax > ELLW) {  // rare (deg > 32), uniform
            int beg = sRP[rloc];
            for (int k = ELLW; k < kmax; ++k) {
                int idx = geidx[beg + k];  // in-bounds (slack); value-select below
                unsigned off = (unsigned)((k < mylen) ? idx : NN) * 16u + (unsigned)c8;
                unsigned long long u = XWu[off];
                unsigned lo = (unsigned)u, hi = (unsigned)(u >> 32);
                a0 += bf_lo(lo); a1 += bf_hi(lo);
                a2 += bf_lo(hi); a3 += bf_hi(hi);
            }
        }
        unsigned rlo = (unsigned)rqw, rhi = (unsigned)(rqw >> 32);
        float dg = (float)mylen;
        float h0 = fmaxf(a0 + fmaf(dg, sw0, sb0), 0.f) + bf_lo(rlo);
        float h1 = fmaxf(a1 + fmaf(dg, sw1, sb1), 0.f) + bf_hi(rlo);
        float h2 = fmaxf(a2 + fmaf(dg, sw2, sb2), 0.f) + bf_lo(rhi);
        float h3 = fmaxf(a3 + fmaf(dg, sw3, sb3), 0.f) + bf_hi(rhi);
        if (grow < n) {
            *(float4*)&hout[(unsigned)grow * 64u + 4u * c8] = make_float4(h0, h1, h2, h3);
            s0 += h0; s1 += h1; s2 += h2; s3 += h3;
            q0 += h0 * h0; q1 += h1 * h1; q2 += h2 * h2; q3 += h3 * h3;
        }
    }

    // reduce across the 4 quarters of the wave (same c8 -> same columns)
    s0 += __shfl_xor(s0, 16, 64); s0 += __shfl_xor(s0, 32, 64);
    s1 += __shfl_xor(s1, 16, 64); s1 += __shfl_xor(s1, 32, 64);
    s2 += __shfl_xor(s2, 16, 64); s2 += __shfl_xor(s2, 32, 64);
    s3 += __shfl_xor(s3, 16, 64); s3 += __shfl_xor(s3, 32, 64);
    q0 += __shfl_xor(q0, 16, 64); q0 += __shfl_xor(q0, 32, 64);
    q1 += __shfl_xor(q1, 16, 64); q1 += __shfl_xor(q1, 32, 64);
    q2 += __shfl_xor(q2, 16, 64); q2 += __shfl_xor(q2, 32, 64);
    q3 += __shfl_xor(q3, 16, 64); q3 += __shfl_xor(q3, 32, 64);
    if (q == 0) {
        lsr[wl][c8][0] = s0; lsr[wl][c8][1] = s1; lsr[wl][c8][2] = s2; lsr[wl][c8][3] = s3;
        lsr[wl][c8][4] = q0; lsr[wl][c8][5] = q1; lsr[wl][c8][6] = q2; lsr[wl][c8][7] = q3;
    }
    __syncthreads();
    if (tid < 64) {
        int c8i = tid >> 2, comp = tid & 3;
        float ssum = lsr[0][c8i][comp] + lsr[1][c8i][comp] + lsr[2][c8i][comp] + lsr[3][c8i][comp];
        float qsum = lsr[0][c8i][4 + comp] + lsr[1][c8i][4 + comp] + lsr[2][c8i][4 + comp] +
                     lsr[3][c8i][4 + comp];
        atomicAdd(&stats[tid], ssum);
        atomicAdd(&stats[64 + tid], qsum);
    }
}

// ---------------- readout ----------------

__global__ void readout_init_kernel(float* __restrict__ hsum, unsigned int* __restrict__ hmax,
                                    const float* __restrict__ stats, const float* __restrict__ g,
                                    const float* __restrict__ be, float* __restrict__ ss) {
    int idx = blockIdx.x * 256 + threadIdx.x;
    if (idx < NB * HD) {
        hsum[idx] = 0.f;
        hmax[idx] = 0x007FFFFFu;  // encoded(-inf)
    }
    if (blockIdx.x == 0 && threadIdx.x < 64) {
        int c = threadIdx.x;
        float mean = stats[c] / (float)NN;
        float var = stats[64 + c] / (float)NN - mean * mean;
        float scale = g[c] * rsqrtf(var + BN_EPS);
        ss[c] = scale;
        ss[64 + c] = be[c] - mean * scale;
    }
}

#define RNODES 16

__device__ __forceinline__ void ro_flush(float* hsum, unsigned int* hmax, int g, int c,
                                         float accS, float accM) {
    atomicAdd(&hsum[g * HD + c], accS);
    unsigned int bits = __float_as_uint(accM);
    unsigned int enc = (bits & 0x80000000u) ? ~bits : (bits | 0x80000000u);
    atomicMax(&hmax[g * HD + c], enc);
}

__global__ __launch_bounds__(256) void readout_kernel(
    const float* __restrict__ h, const int* __restrict__ gid, const float* __restrict__ ss,
    const float* __restrict__ awW, const float* __restrict__ awb, float* __restrict__ hsum,
    unsigned int* __restrict__ hmax, int n) {
    int wid = blockIdx.x * 4 + (threadIdx.x >> 6);
    int c = threadIdx.x & 63;
    int r0 = wid * RNODES;
    if (r0 >= n) return;
    int r1 = r0 + RNODES;
    if (r1 > n) r1 = n;
    float aw = awW[c], ab = awb[0];
    float sA = ss[c], sB = ss[64 + c];
    int cur = gid[r0];
    float accS = 0.f, accM = -__builtin_inff();
    for (int r = r0; r < r1; ++r) {
        int g = gid[r];
        if (g != cur) {
            ro_flush(hsum, hmax, cur, c, accS, accM);
            accS = 0.f;
            accM = -__builtin_inff();
            cur = g;
        }
        float v = fmaf(h[(size_t)r * HD + c], sA, sB);
        float p = v * aw;
        for (int off = 32; off; off >>= 1) p += __shfl_xor(p, off, 64);
        float w = 1.f / (1.f + expf(-(p + ab)));
        accS = fmaf(v, w, accS);
        accM = fmaxf(accM, v);
    }
    ro_flush(hsum, hmax, cur, c, accS, accM);
}

__global__ void final_kernel(const float* __restrict__ hsum, const unsigned int* __restrict__ hmax,
                             const float* __restrict__ outW, const float* __restrict__ outb,
                             float* __restrict__ out) {
    __shared__ float sW[128 * 64];
    for (int i = threadIdx.x; i < 128 * 64; i += 256) sW[i] = outW[i];
    __syncthreads();
    int idx = blockIdx.x * 256 + threadIdx.x;
    if (idx >= NB * HD) return;
    int bi = idx >> 6, o = idx & 63;
    float acc = outb[o];
#pragma unroll 4
    for (int k = 0; k < 64; ++k) acc = fmaf(hsum[bi * 64 + k], sW[k * 64 + o], acc);
#pragma unroll 4
    for (int k = 0; k < 64; ++k) {
        unsigned int e = hmax[bi * 64 + k];
        float m;
        if (e == 0x007FFFFFu) {
            m = 0.f;  // empty graph
        } else {
            m = (e & 0x80000000u) ? __uint_as_float(e ^ 0x80000000u) : __uint_as_float(~e);
        }
        acc = fmaf(m, sW[(64 + k) * 64 + o], acc);
    }
    out[idx] = acc;
}

// ---------------- launch ----------------

extern "C" void kernel_launch(void* const* d_in, const int* in_sizes, int n_in,
                              void* d_out, int out_size, void* d_ws, size_t ws_size,
                              hipStream_t stream) {
    const float* feats = (const float*)d_in[0];
    const int* src = (const int*)d_in[1];
    const int* dst = (const int*)d_in[2];
    const int* gid = (const int*)d_in[3];
    const float* W[3];
    const float* b[3];
    const float* rW[3];
    const float* rb[3];
    const float* g[3];
    const float* be[3];
    for (int l = 0; l < 3; ++l) {
        W[l] = (const float*)d_in[4 + 6 * l + 0];
        b[l] = (const float*)d_in[4 + 6 * l + 1];
        rW[l] = (const float*)d_in[4 + 6 * l + 2];
        rb[l] = (const float*)d_in[4 + 6 * l + 3];
        g[l] = (const float*)d_in[4 + 6 * l + 4];
        be[l] = (const float*)d_in[4 + 6 * l + 5];
    }
    const float* awW = (const float*)d_in[22];
    const float* awb = (const float*)d_in[23];
    const float* outW = (const float*)d_in[24];
    const float* outb = (const float*)d_in[25];
    float* out = (float*)d_out;

    // workspace layout
    __hip_bfloat16* XW = (__hip_bfloat16*)d_ws;                 // (NN+1)*64 bf16 (row NN zeros)
    __hip_bfloat16* RES = XW + (size_t)(NN + 1) * HD;           // NN*64 bf16
    float* P1 = (float*)(RES + (size_t)NN * HD);                // N*64 f32 (h, in place)
    float* stats = P1 + (size_t)NN * HD;                        // 3*128
    float* ss2 = stats + 384;                                   // 128
    float2* WPK = (float2*)(ss2 + 128);                         // FIN*HD float2
    float* shW = (float*)(WPK + FIN * HD);                      // 64
    float* rbp = shW + 64;                                      // 64
    float* hsum = rbp + 64;                                     // B*64
    unsigned int* hmax = (unsigned int*)(hsum + (size_t)NB * HD);  // B*64
    int* cnt = (int*)(hmax + (size_t)NB * HD);                  // N
    int* cnt2 = cnt + NN;                                       // N
    int* row_ptr = cnt2 + NN;                                   // N+1
    int* bsum = row_ptr + NN + 1;                               // NCHUNK
    int* eidx = bsum + NCHUNK;                                  // NE + 64 slack

    float* stats0 = stats;
    float* stats1 = stats + 128;
    float* stats2 = stats + 256;

    const int EBLK = (NE + 255) / 256;
    const int GEMMBLK = 1280;
    const int ROBLK = (NN + RNODES * 4 - 1) / (RNODES * 4);

    // ---- CSR build + layer-0 weight pack ----
    csr_zero_kernel<<<(NN + 255) / 256, 256, 0, stream>>>(
        cnt, cnt2, stats, (unsigned long long*)(XW + (size_t)NN * HD), W[0], rW[0], WPK);
    csr_hist_kernel<<<EBLK, 256, 0, stream>>>(dst, cnt);
    scanA_kernel<<<NCHUNK, SCHUNK, 0, stream>>>(cnt, bsum);
    scanB_kernel<<<1, 64, 0, stream>>>(bsum);
    scanC_kernel<<<NCHUNK, SCHUNK, 0, stream>>>(cnt, bsum, row_ptr);
    csr_fill_kernel<<<EBLK, 256, 0, stream>>>(src, dst, row_ptr, cnt2, eidx);

    // ---- layer 0 ----
    gemm_dual_kernel<FIN><<<GEMMBLK, 256, 0, stream>>>(feats, WPK, rb[0], XW, RES, NN);
    fused_agg_kernel<<<NBLK, 256, 0, stream>>>(XW, RES, b[0], (const float*)nullptr, row_ptr,
                                               eidx, P1, stats0, NN);

    // ---- layer 1 (fold BN0) ----
    fold_kernel<<<1, 256, 0, stream>>>(stats0, g[0], be[0], W[1], rW[1], rb[1], WPK, shW, rbp);
    gemm_dual_kernel<HD><<<GEMMBLK, 256, 0, stream>>>(P1, WPK, rbp, XW, RES, NN);
    fused_agg_kernel<<<NBLK, 256, 0, stream>>>(XW, RES, b[1], shW, row_ptr, eidx, P1, stats1, NN);

    // ---- layer 2 (fold BN1) ----
    fold_kernel<<<1, 256, 0, stream>>>(stats1, g[1], be[1], W[2], rW[2], rb[2], WPK, shW, rbp);
    gemm_dual_kernel<HD><<<GEMMBLK, 256, 0, stream>>>(P1, WPK, rbp, XW, RES, NN);
    fused_agg_kernel<<<NBLK, 256, 0, stream>>>(XW, RES, b[2], shW, row_ptr, eidx, P1, stats2, NN);

    // ---- readout (BN2 on the fly) ----
    readout_init_kernel<<<(NB * HD + 255) / 256, 256, 0, stream>>>(hsum, hmax, stats2, g[2], be[2], ss2);
    readout_kernel<<<ROBLK, 256, 0, stream>>>(P1, gid, ss2, awW, awb, hsum, hmax, NN);
    final_kernel<<<(NB * HD + 255) / 256, 256, 0, stream>>>(hsum, hmax, outW, outb, out);
}